// Round 21
// baseline (138.951 us; speedup 1.0000x reference)
//
#include <hip/hip_runtime.h>
#include <hip/hip_fp16.h>

#define NN 50000
#define EE 800000
#define DD 96

#define NBIN 196            // coarse bins of 256 dst nodes: bin = d >> 8
#define CE   4096           // edges per phase-1 block
#define CB   196            // ceil(EE / CE) phase-1 blocks
#define EPT2 16             // CE / 256 edges per thread

// Harness passes integer inputs as int32 — edge_index is const int* (2,E).
// Lessons: (r7) cross-XCD global atomics = memory-side full-line RMW ->
// LDS-only atomics + coalesced writes. (r8) single-block scans of >10K elems
// are ~60us latency holes -> per-bin parallel scans. (r10) gather traffic ~
// E*row_bytes -> fp16 staging. (r11) aggregate-then-transform fuses a layer.
// (r12) 32node x 12lane x 4-wide gather = best gather form. (r13) cooperative
// fusion caps width. (r14) 8-wide regressed. (r15) 384-thr wave-capped at 5
// blocks/CU. (r16) split-degree null. (r17) col-prefetch null. (r18/r19)
// degree-sort perm net-negative. (r20) killed per-edge binary search ->
// 125.5us best. (r21) FETCH=68MB is compulsory but r5 proved 2TB/s gather
// feasible -> k_fused is scheduling-pinned, not BW-pinned; drop W from LDS
// for 192-thr/16-node blocks at 10 blocks/CU (finer quanta, no W cvt).

// ---- 1a: coarse histogram per edge-chunk --------------------------------

__global__ __launch_bounds__(256) void k_hist(const int* __restrict__ ei,
                                              int* __restrict__ histB) {
    __shared__ int hist[NBIN];
    int t = threadIdx.x;
    if (t < NBIN) hist[t] = 0;
    __syncthreads();
    int e0 = blockIdx.x * CE;
#pragma unroll
    for (int k = 0; k < EPT2; ++k) {
        int e = e0 + k * 256 + t;
        if (e < EE) atomicAdd(&hist[ei[EE + e] >> 8], 1);
    }
    __syncthreads();
    if (t < NBIN) histB[t * CB + blockIdx.x] = hist[t];  // bin-major
}

// ---- 1b: per-bin row scan (196 blocks, one row each) --------------------

__global__ __launch_bounds__(256) void k_scan_bins(int* __restrict__ histB,
                                                   int* __restrict__ binTot) {
    __shared__ int sh[256];
    int t = threadIdx.x;
    int b = blockIdx.x;
    int v = (t < CB) ? histB[b * CB + t] : 0;
    sh[t] = v;
    __syncthreads();
    for (int off = 1; off < 256; off <<= 1) {
        int u = (t >= off) ? sh[t - off] : 0;
        __syncthreads();
        sh[t] += u;
        __syncthreads();
    }
    if (t < CB) histB[b * CB + t] = sh[t] - v;   // exclusive within bin
    if (t == 255) binTot[b] = sh[255];           // bin total
}

// ---- 1c: bin-scatter into packed[] (bin byte packed -> no binary search) --

__global__ __launch_bounds__(256) void k_scatter_bins(const int* __restrict__ ei,
                                                      const int* __restrict__ histB,
                                                      const int* __restrict__ binTot,
                                                      int* __restrict__ packed) {
    __shared__ int hist[NBIN];
    __shared__ int lofs[NBIN];
    __shared__ int cur[NBIN];
    __shared__ int sstart[NBIN];
    __shared__ unsigned buf[CE];
    __shared__ int sh[256];
    int t = threadIdx.x;
    int e0 = blockIdx.x * CE;
    int nE = min(CE, EE - e0);

    int s[EPT2], d[EPT2];
#pragma unroll
    for (int k = 0; k < EPT2; ++k) {
        int e = e0 + k * 256 + t;
        s[k] = (e < EE) ? ei[e] : 0;
        d[k] = (e < EE) ? ei[EE + e] : -1;
    }
    // local binbase = exclusive scan of binTot (196 elems)
    int bt = (t < NBIN) ? binTot[t] : 0;
    sh[t] = bt;
    __syncthreads();
    for (int off = 1; off < 256; off <<= 1) {
        int u = (t >= off) ? sh[t - off] : 0;
        __syncthreads();
        sh[t] += u;
        __syncthreads();
    }
    int mybinbase = sh[t] - bt;
    __syncthreads();

    if (t < NBIN) hist[t] = 0;
    __syncthreads();
#pragma unroll
    for (int k = 0; k < EPT2; ++k)
        if (d[k] >= 0) atomicAdd(&hist[d[k] >> 8], 1);
    __syncthreads();
    int v = (t < NBIN) ? hist[t] : 0;
    sh[t] = v;
    __syncthreads();
    for (int off = 1; off < 256; off <<= 1) {
        int u = (t >= off) ? sh[t - off] : 0;
        __syncthreads();
        sh[t] += u;
        __syncthreads();
    }
    if (t < NBIN) { lofs[t] = sh[t] - v; cur[t] = sh[t] - v; }
    if (t < NBIN) sstart[t] = mybinbase + histB[t * CB + blockIdx.x];
    __syncthreads();
#pragma unroll
    for (int k = 0; k < EPT2; ++k)
        if (d[k] >= 0) {
            int b = d[k] >> 8;                    // < 196, fits 8 bits
            int pos = atomicAdd(&cur[b], 1);
            // pack: s (16b) | dlow (8b) | bin (8b)
            buf[pos] = (unsigned)s[k] | ((unsigned)(d[k] & 0xFF) << 16)
                                      | ((unsigned)b << 24);
        }
    __syncthreads();
    for (int i = t; i < nE; i += 256) {
        unsigned pv = buf[i];
        int bin = pv >> 24;                       // direct lookup, no search
        packed[sstart[bin] + (i - lofs[bin])] = (int)pv;
    }
}

// ---- 2: per-bin CSR (rp, dinv, col) + fused x->xh cvt -------------------

__global__ __launch_bounds__(256) void k_csr(const int* __restrict__ packed,
                                             const int* __restrict__ binTot,
                                             int* __restrict__ rp,
                                             float* __restrict__ dinv,
                                             int* __restrict__ col,
                                             const float* __restrict__ x,
                                             __half* __restrict__ xh) {
    __shared__ int h256[256];
    __shared__ int cur[256];
    __shared__ int sh[256];
    __shared__ float sdinv[256];
    __shared__ int s_base, s_n;
    int t = threadIdx.x;
    int b = blockIdx.x;

    // local binbase scan: base = excl-prefix at b, nE = binTot[b]
    int bt = (t < NBIN) ? binTot[t] : 0;
    sh[t] = bt;
    __syncthreads();
    for (int off = 1; off < 256; off <<= 1) {
        int u = (t >= off) ? sh[t - off] : 0;
        __syncthreads();
        sh[t] += u;
        __syncthreads();
    }
    if (t == b) { s_base = sh[t] - bt; s_n = bt; }
    __syncthreads();
    int base = s_base;
    int nE = s_n;

    h256[t] = 0;
    __syncthreads();
    for (int i = t; i < nE; i += 256)
        atomicAdd(&h256[(packed[base + i] >> 16) & 0xFF], 1);
    __syncthreads();
    int v = h256[t];
    sh[t] = v;
    __syncthreads();
    for (int off = 1; off < 256; off <<= 1) {
        int u = (t >= off) ? sh[t - off] : 0;
        __syncthreads();
        sh[t] += u;
        __syncthreads();
    }
    int ex = sh[t] - v;
    cur[t] = ex;
    float di = rsqrtf((float)(v + 1));           // +1 self-loop
    sdinv[t] = di;
    int node = b * 256 + t;
    if (node <= NN) rp[node] = base + ex;        // node==NN lands on EE
    if (node < NN) dinv[node] = di;
    __syncthreads();
    for (int i = t; i < nE; i += 256) {
        int pv = packed[base + i];
        int pos = atomicAdd(&cur[(pv >> 16) & 0xFF], 1);
        col[base + pos] = pv & 0xFFFF;
    }
    // fused cvt: xh[r] = fp16(sdinv .* x[r]) for this block's 256 rows
    for (int i = t; i < 256 * 12; i += 256) {
        int rr = i / 12;                          // 0..255
        int cc = i % 12;                          // half8 chunk
        int r = b * 256 + rr;
        if (r < NN) {
            float sc = sdinv[rr];
            const float4* xx = (const float4*)x + (size_t)r * 24 + cc * 2;
            float4 f0 = xx[0], f1 = xx[1];
            __half h[8];
            h[0] = __float2half_rn(sc * f0.x); h[1] = __float2half_rn(sc * f0.y);
            h[2] = __float2half_rn(sc * f0.z); h[3] = __float2half_rn(sc * f0.w);
            h[4] = __float2half_rn(sc * f1.x); h[5] = __float2half_rn(sc * f1.y);
            h[6] = __float2half_rn(sc * f1.z); h[7] = __float2half_rn(sc * f1.w);
            ((uint4*)xh)[(size_t)r * 12 + cc] = *(uint4*)h;
        }
    }
}

// ---- 3: fused layer = gather(agg) -> LDS -> @W + b -> relu ----------------
// r21 form: 192 thr = 16 nodes x 12 half8-lanes; Al[16][100] is the ONLY LDS
// (6.4 KB) -> 10 blocks/CU x 3 waves = 30 waves at 2x finer granularity.
// Phase B reads W f32 straight from global (36 KB, L2-hot broadcast row/iter;
// no fp16-W cvt, no W quantization). Gather loop = r12/r20's measured-best.

template <int FINAL>
__global__ __launch_bounds__(192) void k_fused(const __half* __restrict__ xh,
                                               const int* __restrict__ rp,
                                               const int* __restrict__ col,
                                               const float* __restrict__ dinv,
                                               const float* __restrict__ W,
                                               const float* __restrict__ b,
                                               __half* __restrict__ acth,
                                               float* __restrict__ outf) {
    __shared__ float Al[16][100];     // f32 agg tile, +4 pad (6400 B)
    int t = threadIdx.x;

    int c  = t % 12;                  // half8 column
    int ny = t / 12;                  // 0..15
    int d = blockIdx.x * 16 + ny;     // grid divides NN exactly (3125*16)
    const uint4* h4 = (const uint4*)xh;   // row stride 12

    if (d < NN) {
        union U { uint4 u; __half2 h[4]; };
        U self; self.u = h4[d * 12 + c];    // self-loop row (pre-scaled)
        float dd = dinv[d];
        int j0 = rp[d], j1 = rp[d + 1];

        float2 aA[4] = {{0,0},{0,0},{0,0},{0,0}};
        float2 aB[4] = {{0,0},{0,0},{0,0},{0,0}};
        int j = j0;
        for (; j + 3 < j1; j += 4) {
            int s0 = col[j], s1 = col[j+1], s2 = col[j+2], s3 = col[j+3];
            U v0, v1, v2, v3;
            v0.u = h4[s0 * 12 + c];
            v1.u = h4[s1 * 12 + c];
            v2.u = h4[s2 * 12 + c];
            v3.u = h4[s3 * 12 + c];
#pragma unroll
            for (int k = 0; k < 4; ++k) {
                float2 f0 = __half22float2(v0.h[k]);
                float2 f1 = __half22float2(v1.h[k]);
                float2 f2 = __half22float2(v2.h[k]);
                float2 f3 = __half22float2(v3.h[k]);
                aA[k].x += f0.x + f1.x; aA[k].y += f0.y + f1.y;
                aB[k].x += f2.x + f3.x; aB[k].y += f2.y + f3.y;
            }
        }
        for (; j < j1; ++j) {
            U v; v.u = h4[col[j] * 12 + c];
#pragma unroll
            for (int k = 0; k < 4; ++k) {
                float2 f = __half22float2(v.h[k]);
                aA[k].x += f.x; aA[k].y += f.y;
            }
        }
        float v[8];
#pragma unroll
        for (int k = 0; k < 4; ++k) {
            float2 fs = __half22float2(self.h[k]);
            v[2*k]   = dd * (aA[k].x + aB[k].x + fs.x);
            v[2*k+1] = dd * (aA[k].y + aB[k].y + fs.y);
        }
        *(float4*)&Al[ny][c * 8]     = make_float4(v[0], v[1], v[2], v[3]);
        *(float4*)&Al[ny][c * 8 + 4] = make_float4(v[4], v[5], v[6], v[7]);
    }
    __syncthreads();

    // Phase B: out_tile = Al @ W + b, relu, write. W read f32 from global
    // (row k broadcast: 24 distinct float4 per iter, L2-hot).
    int tx = t % 24;                  // col4 group
    int ry = t / 24;                  // rows ry, ry+8
    int c0 = tx * 4;
    const float4* W4 = (const float4*)W;   // row stride 24 float4s
    float a0x = 0.f, a0y = 0.f, a0z = 0.f, a0w = 0.f;
    float a1x = 0.f, a1y = 0.f, a1z = 0.f, a1w = 0.f;
#pragma unroll 8
    for (int k = 0; k < DD; ++k) {
        float4 w = W4[k * 24 + tx];
        float r0 = Al[ry][k];
        float r1 = Al[ry + 8][k];
        a0x += r0 * w.x; a0y += r0 * w.y; a0z += r0 * w.z; a0w += r0 * w.w;
        a1x += r1 * w.x; a1y += r1 * w.y; a1z += r1 * w.z; a1w += r1 * w.w;
    }
    float4 bb = *(const float4*)&b[c0];
    int g0 = blockIdx.x * 16 + ry;
    int g1 = g0 + 8;
    float r0x = fmaxf(a0x + bb.x, 0.f), r0y = fmaxf(a0y + bb.y, 0.f);
    float r0z = fmaxf(a0z + bb.z, 0.f), r0w = fmaxf(a0w + bb.w, 0.f);
    float r1x = fmaxf(a1x + bb.x, 0.f), r1y = fmaxf(a1y + bb.y, 0.f);
    float r1z = fmaxf(a1z + bb.z, 0.f), r1w = fmaxf(a1w + bb.w, 0.f);
    if (g0 < NN) {
        if (FINAL) {
            *(float4*)&outf[g0 * DD + c0] = make_float4(r0x, r0y, r0z, r0w);
        } else {
            float sc = dinv[g0];
            __half h[4];
            h[0] = __float2half_rn(sc * r0x); h[1] = __float2half_rn(sc * r0y);
            h[2] = __float2half_rn(sc * r0z); h[3] = __float2half_rn(sc * r0w);
            *(uint2*)&acth[g0 * DD + c0] = *(uint2*)h;
        }
    }
    if (g1 < NN) {
        if (FINAL) {
            *(float4*)&outf[g1 * DD + c0] = make_float4(r1x, r1y, r1z, r1w);
        } else {
            float sc = dinv[g1];
            __half h[4];
            h[0] = __float2half_rn(sc * r1x); h[1] = __float2half_rn(sc * r1y);
            h[2] = __float2half_rn(sc * r1z); h[3] = __float2half_rn(sc * r1w);
            *(uint2*)&acth[g1 * DD + c0] = *(uint2*)h;
        }
    }
}

// ----------------------------------------------------------------------------

extern "C" void kernel_launch(void* const* d_in, const int* in_sizes, int n_in,
                              void* d_out, int out_size, void* d_ws, size_t ws_size,
                              hipStream_t stream) {
    const float* x  = (const float*)d_in[0];
    const int*   ei = (const int*)d_in[1];
    const float* W1 = (const float*)d_in[2];
    const float* b1 = (const float*)d_in[3];
    const float* W2 = (const float*)d_in[4];
    const float* b2 = (const float*)d_in[5];
    float* out = (float*)d_out;

    // Workspace (~22.9 MB). packed[] aliases bufB (dead until k_fused<0>);
    // k_csr writes bufA=xh while other blocks still read packed.
    char* p = (char*)d_ws;
    int*   histB   = (int*)p;   p += ((size_t)NBIN * CB * 4 + 255) & ~(size_t)255;
    int*   binTot  = (int*)p;   p += ((size_t)NBIN * 4 + 255) & ~(size_t)255;
    int*   rp      = (int*)p;   p += ((size_t)(NN + 1) * 4 + 255) & ~(size_t)255;
    float* dinv    = (float*)p; p += ((size_t)NN * 4 + 255) & ~(size_t)255;
    int*   col     = (int*)p;   p += ((size_t)EE * 4 + 255) & ~(size_t)255;
    __half* bufA   = (__half*)p; p += ((size_t)NN * DD * 2 + 255) & ~(size_t)255;
    __half* bufB   = (__half*)p;                  // N*D halves (9.6 MB)
    int*   packed  = (int*)bufB;                  // EE ints, alias (dead early)

    // ---- CSR build: 4 dispatches, no global atomics, no serial scans ----
    k_hist<<<CB, 256, 0, stream>>>(ei, histB);
    k_scan_bins<<<NBIN, 256, 0, stream>>>(histB, binTot);
    k_scatter_bins<<<CB, 256, 0, stream>>>(ei, histB, binTot, packed);
    k_csr<<<NBIN, 256, 0, stream>>>(packed, binTot, rp, dinv, col, x, bufA);

    // ---- layer 1 (fused): bufB = fp16(dinv .* relu(agg(bufA) @ W1 + b1)) ----
    k_fused<0><<<(NN + 15) / 16, 192, 0, stream>>>(bufA, rp, col, dinv, W1, b1,
                                                   bufB, nullptr);

    // ---- layer 2 (fused): d_out = relu(agg(bufB) @ W2 + b2) ----
    k_fused<1><<<(NN + 15) / 16, 192, 0, stream>>>(bufB, rp, col, dinv, W2, b2,
                                                   nullptr, out);
}

// Round 22
// 125.170 us; speedup vs baseline: 1.1101x; 1.1101x over previous
//
#include <hip/hip_runtime.h>
#include <hip/hip_fp16.h>

#define NN 50000
#define EE 800000
#define DD 96

#define NBIN 196            // coarse bins of 256 dst nodes: bin = d >> 8
#define CE   4096           // edges per phase-1 block
#define CB   196            // ceil(EE / CE) phase-1 blocks
#define EPT2 16             // CE / 256 edges per thread

// Harness passes integer inputs as int32 — edge_index is const int* (2,E).
// Lessons: (r7) cross-XCD global atomics = memory-side full-line RMW ->
// LDS-only atomics + coalesced writes. (r8) single-block scans of >10K elems
// are ~60us latency holes -> per-bin parallel scans. (r10) gather traffic ~
// E*row_bytes -> fp16 staging. (r11) aggregate-then-transform fuses a layer.
// (r12) W as fp16 in LDS; 32node x 12lane x 4-wide gather = best k_fused
// (47.7us). (r13) cooperative fusion caps width. (r14) 8-wide regressed.
// (r15) wave-capped at 5 blocks/CU. (r16) split-degree null. (r17)
// col-prefetch null. (r18/r19) degree-sort perm net-negative. (r20) killed
// per-edge binary search -> 125.5us best. (r21) W-from-global regressed
// (phase B stalls on L2 W rows; occupancy is NOT the binder) -> revert.

// ---- 1a: coarse histogram per edge-chunk --------------------------------

__global__ __launch_bounds__(256) void k_hist(const int* __restrict__ ei,
                                              int* __restrict__ histB) {
    __shared__ int hist[NBIN];
    int t = threadIdx.x;
    if (t < NBIN) hist[t] = 0;
    __syncthreads();
    int e0 = blockIdx.x * CE;
#pragma unroll
    for (int k = 0; k < EPT2; ++k) {
        int e = e0 + k * 256 + t;
        if (e < EE) atomicAdd(&hist[ei[EE + e] >> 8], 1);
    }
    __syncthreads();
    if (t < NBIN) histB[t * CB + blockIdx.x] = hist[t];  // bin-major
}

// ---- 1b: per-bin row scan (196 blocks, one row each) --------------------

__global__ __launch_bounds__(256) void k_scan_bins(int* __restrict__ histB,
                                                   int* __restrict__ binTot) {
    __shared__ int sh[256];
    int t = threadIdx.x;
    int b = blockIdx.x;
    int v = (t < CB) ? histB[b * CB + t] : 0;
    sh[t] = v;
    __syncthreads();
    for (int off = 1; off < 256; off <<= 1) {
        int u = (t >= off) ? sh[t - off] : 0;
        __syncthreads();
        sh[t] += u;
        __syncthreads();
    }
    if (t < CB) histB[b * CB + t] = sh[t] - v;   // exclusive within bin
    if (t == 255) binTot[b] = sh[255];           // bin total
}

// ---- 1c: bin-scatter into packed[] (bin byte packed -> no binary search) --

__global__ __launch_bounds__(256) void k_scatter_bins(const int* __restrict__ ei,
                                                      const int* __restrict__ histB,
                                                      const int* __restrict__ binTot,
                                                      int* __restrict__ packed) {
    __shared__ int hist[NBIN];
    __shared__ int lofs[NBIN];
    __shared__ int cur[NBIN];
    __shared__ int sstart[NBIN];
    __shared__ unsigned buf[CE];
    __shared__ int sh[256];
    int t = threadIdx.x;
    int e0 = blockIdx.x * CE;
    int nE = min(CE, EE - e0);

    int s[EPT2], d[EPT2];
#pragma unroll
    for (int k = 0; k < EPT2; ++k) {
        int e = e0 + k * 256 + t;
        s[k] = (e < EE) ? ei[e] : 0;
        d[k] = (e < EE) ? ei[EE + e] : -1;
    }
    // local binbase = exclusive scan of binTot (196 elems)
    int bt = (t < NBIN) ? binTot[t] : 0;
    sh[t] = bt;
    __syncthreads();
    for (int off = 1; off < 256; off <<= 1) {
        int u = (t >= off) ? sh[t - off] : 0;
        __syncthreads();
        sh[t] += u;
        __syncthreads();
    }
    int mybinbase = sh[t] - bt;
    __syncthreads();

    if (t < NBIN) hist[t] = 0;
    __syncthreads();
#pragma unroll
    for (int k = 0; k < EPT2; ++k)
        if (d[k] >= 0) atomicAdd(&hist[d[k] >> 8], 1);
    __syncthreads();
    int v = (t < NBIN) ? hist[t] : 0;
    sh[t] = v;
    __syncthreads();
    for (int off = 1; off < 256; off <<= 1) {
        int u = (t >= off) ? sh[t - off] : 0;
        __syncthreads();
        sh[t] += u;
        __syncthreads();
    }
    if (t < NBIN) { lofs[t] = sh[t] - v; cur[t] = sh[t] - v; }
    if (t < NBIN) sstart[t] = mybinbase + histB[t * CB + blockIdx.x];
    __syncthreads();
#pragma unroll
    for (int k = 0; k < EPT2; ++k)
        if (d[k] >= 0) {
            int b = d[k] >> 8;                    // < 196, fits 8 bits
            int pos = atomicAdd(&cur[b], 1);
            // pack: s (16b) | dlow (8b) | bin (8b)
            buf[pos] = (unsigned)s[k] | ((unsigned)(d[k] & 0xFF) << 16)
                                      | ((unsigned)b << 24);
        }
    __syncthreads();
    for (int i = t; i < nE; i += 256) {
        unsigned pv = buf[i];
        int bin = pv >> 24;                       // direct lookup, no search
        packed[sstart[bin] + (i - lofs[bin])] = (int)pv;
    }
}

// ---- 2: per-bin CSR (rp, dinv, col) + fused x->xh cvt -------------------

__global__ __launch_bounds__(256) void k_csr(const int* __restrict__ packed,
                                             const int* __restrict__ binTot,
                                             int* __restrict__ rp,
                                             float* __restrict__ dinv,
                                             int* __restrict__ col,
                                             const float* __restrict__ x,
                                             __half* __restrict__ xh) {
    __shared__ int h256[256];
    __shared__ int cur[256];
    __shared__ int sh[256];
    __shared__ float sdinv[256];
    __shared__ int s_base, s_n;
    int t = threadIdx.x;
    int b = blockIdx.x;

    // local binbase scan: base = excl-prefix at b, nE = binTot[b]
    int bt = (t < NBIN) ? binTot[t] : 0;
    sh[t] = bt;
    __syncthreads();
    for (int off = 1; off < 256; off <<= 1) {
        int u = (t >= off) ? sh[t - off] : 0;
        __syncthreads();
        sh[t] += u;
        __syncthreads();
    }
    if (t == b) { s_base = sh[t] - bt; s_n = bt; }
    __syncthreads();
    int base = s_base;
    int nE = s_n;

    h256[t] = 0;
    __syncthreads();
    for (int i = t; i < nE; i += 256)
        atomicAdd(&h256[(packed[base + i] >> 16) & 0xFF], 1);
    __syncthreads();
    int v = h256[t];
    sh[t] = v;
    __syncthreads();
    for (int off = 1; off < 256; off <<= 1) {
        int u = (t >= off) ? sh[t - off] : 0;
        __syncthreads();
        sh[t] += u;
        __syncthreads();
    }
    int ex = sh[t] - v;
    cur[t] = ex;
    float di = rsqrtf((float)(v + 1));           // +1 self-loop
    sdinv[t] = di;
    int node = b * 256 + t;
    if (node <= NN) rp[node] = base + ex;        // node==NN lands on EE
    if (node < NN) dinv[node] = di;
    __syncthreads();
    for (int i = t; i < nE; i += 256) {
        int pv = packed[base + i];
        int pos = atomicAdd(&cur[(pv >> 16) & 0xFF], 1);
        col[base + pos] = pv & 0xFFFF;
    }
    // fused cvt: xh[r] = fp16(sdinv .* x[r]) for this block's 256 rows
    for (int i = t; i < 256 * 12; i += 256) {
        int rr = i / 12;                          // 0..255
        int cc = i % 12;                          // half8 chunk
        int r = b * 256 + rr;
        if (r < NN) {
            float sc = sdinv[rr];
            const float4* xx = (const float4*)x + (size_t)r * 24 + cc * 2;
            float4 f0 = xx[0], f1 = xx[1];
            __half h[8];
            h[0] = __float2half_rn(sc * f0.x); h[1] = __float2half_rn(sc * f0.y);
            h[2] = __float2half_rn(sc * f0.z); h[3] = __float2half_rn(sc * f0.w);
            h[4] = __float2half_rn(sc * f1.x); h[5] = __float2half_rn(sc * f1.y);
            h[6] = __float2half_rn(sc * f1.z); h[7] = __float2half_rn(sc * f1.w);
            ((uint4*)xh)[(size_t)r * 12 + cc] = *(uint4*)h;
        }
    }
}

// ---- 3: fused layer = gather(agg) -> LDS -> @W + b -> relu ----------------
// r12's measured-best form: 32 nodes x 12 half8-lanes, 4-wide gather,
// f32 Al, fp16 W in LDS, no perm indirection.

template <int FINAL>
__global__ __launch_bounds__(384) void k_fused(const __half* __restrict__ xh,
                                               const int* __restrict__ rp,
                                               const int* __restrict__ col,
                                               const float* __restrict__ dinv,
                                               const float* __restrict__ W,
                                               const float* __restrict__ b,
                                               __half* __restrict__ acth,
                                               float* __restrict__ outf) {
    __shared__ __half Wl[DD * DD];    // fp16 W, row-major (18432 B)
    __shared__ float Al[32][100];     // f32 agg tile, +4 pad (12800 B)
    int t = threadIdx.x;
    for (int i = t; i < DD * DD / 8; i += 384) {
        const float4* ww = (const float4*)W;
        float4 f0 = ww[i * 2], f1 = ww[i * 2 + 1];
        __half h[8];
        h[0] = __float2half_rn(f0.x); h[1] = __float2half_rn(f0.y);
        h[2] = __float2half_rn(f0.z); h[3] = __float2half_rn(f0.w);
        h[4] = __float2half_rn(f1.x); h[5] = __float2half_rn(f1.y);
        h[6] = __float2half_rn(f1.z); h[7] = __float2half_rn(f1.w);
        ((uint4*)Wl)[i] = *(uint4*)h;
    }

    int c  = t % 12;                  // half8 column
    int ny = t / 12;                  // 0..31
    int d = blockIdx.x * 32 + ny;
    const uint4* h4 = (const uint4*)xh;   // row stride 12

    if (d < NN) {
        union U { uint4 u; __half2 h[4]; };
        U self; self.u = h4[d * 12 + c];    // self-loop row (pre-scaled)
        float dd = dinv[d];
        int j0 = rp[d], j1 = rp[d + 1];

        float2 aA[4] = {{0,0},{0,0},{0,0},{0,0}};
        float2 aB[4] = {{0,0},{0,0},{0,0},{0,0}};
        int j = j0;
        for (; j + 3 < j1; j += 4) {
            int s0 = col[j], s1 = col[j+1], s2 = col[j+2], s3 = col[j+3];
            U v0, v1, v2, v3;
            v0.u = h4[s0 * 12 + c];
            v1.u = h4[s1 * 12 + c];
            v2.u = h4[s2 * 12 + c];
            v3.u = h4[s3 * 12 + c];
#pragma unroll
            for (int k = 0; k < 4; ++k) {
                float2 f0 = __half22float2(v0.h[k]);
                float2 f1 = __half22float2(v1.h[k]);
                float2 f2 = __half22float2(v2.h[k]);
                float2 f3 = __half22float2(v3.h[k]);
                aA[k].x += f0.x + f1.x; aA[k].y += f0.y + f1.y;
                aB[k].x += f2.x + f3.x; aB[k].y += f2.y + f3.y;
            }
        }
        for (; j < j1; ++j) {
            U v; v.u = h4[col[j] * 12 + c];
#pragma unroll
            for (int k = 0; k < 4; ++k) {
                float2 f = __half22float2(v.h[k]);
                aA[k].x += f.x; aA[k].y += f.y;
            }
        }
        float v[8];
#pragma unroll
        for (int k = 0; k < 4; ++k) {
            float2 fs = __half22float2(self.h[k]);
            v[2*k]   = dd * (aA[k].x + aB[k].x + fs.x);
            v[2*k+1] = dd * (aA[k].y + aB[k].y + fs.y);
        }
        *(float4*)&Al[ny][c * 8]     = make_float4(v[0], v[1], v[2], v[3]);
        *(float4*)&Al[ny][c * 8 + 4] = make_float4(v[4], v[5], v[6], v[7]);
    }
    __syncthreads();

    // Phase B: out_tile = Al @ W + b, relu, write.
    int tx = t % 24;                  // col4 group
    int ry = t / 24;                  // rows ry, ry+16
    int c0 = tx * 4;
    float a0x = 0.f, a0y = 0.f, a0z = 0.f, a0w = 0.f;
    float a1x = 0.f, a1y = 0.f, a1z = 0.f, a1w = 0.f;
#pragma unroll 8
    for (int k = 0; k < DD; ++k) {
        uint2 wv = *(const uint2*)&Wl[k * DD + c0];   // 4 halves
        const __half2* wh = (const __half2*)&wv;
        float2 w01 = __half22float2(wh[0]);
        float2 w23 = __half22float2(wh[1]);
        float r0 = Al[ry][k];
        float r1 = Al[ry + 16][k];
        a0x += r0 * w01.x; a0y += r0 * w01.y; a0z += r0 * w23.x; a0w += r0 * w23.y;
        a1x += r1 * w01.x; a1y += r1 * w01.y; a1z += r1 * w23.x; a1w += r1 * w23.y;
    }
    float4 bb = *(const float4*)&b[c0];
    int g0 = blockIdx.x * 32 + ry;
    int g1 = g0 + 16;
    float r0x = fmaxf(a0x + bb.x, 0.f), r0y = fmaxf(a0y + bb.y, 0.f);
    float r0z = fmaxf(a0z + bb.z, 0.f), r0w = fmaxf(a0w + bb.w, 0.f);
    float r1x = fmaxf(a1x + bb.x, 0.f), r1y = fmaxf(a1y + bb.y, 0.f);
    float r1z = fmaxf(a1z + bb.z, 0.f), r1w = fmaxf(a1w + bb.w, 0.f);
    if (g0 < NN) {
        if (FINAL) {
            *(float4*)&outf[g0 * DD + c0] = make_float4(r0x, r0y, r0z, r0w);
        } else {
            float sc = dinv[g0];
            __half h[4];
            h[0] = __float2half_rn(sc * r0x); h[1] = __float2half_rn(sc * r0y);
            h[2] = __float2half_rn(sc * r0z); h[3] = __float2half_rn(sc * r0w);
            *(uint2*)&acth[g0 * DD + c0] = *(uint2*)h;
        }
    }
    if (g1 < NN) {
        if (FINAL) {
            *(float4*)&outf[g1 * DD + c0] = make_float4(r1x, r1y, r1z, r1w);
        } else {
            float sc = dinv[g1];
            __half h[4];
            h[0] = __float2half_rn(sc * r1x); h[1] = __float2half_rn(sc * r1y);
            h[2] = __float2half_rn(sc * r1z); h[3] = __float2half_rn(sc * r1w);
            *(uint2*)&acth[g1 * DD + c0] = *(uint2*)h;
        }
    }
}

// ----------------------------------------------------------------------------

extern "C" void kernel_launch(void* const* d_in, const int* in_sizes, int n_in,
                              void* d_out, int out_size, void* d_ws, size_t ws_size,
                              hipStream_t stream) {
    const float* x  = (const float*)d_in[0];
    const int*   ei = (const int*)d_in[1];
    const float* W1 = (const float*)d_in[2];
    const float* b1 = (const float*)d_in[3];
    const float* W2 = (const float*)d_in[4];
    const float* b2 = (const float*)d_in[5];
    float* out = (float*)d_out;

    // Workspace (~22.9 MB). packed[] aliases bufB (dead until k_fused<0>);
    // k_csr writes bufA=xh while other blocks still read packed.
    char* p = (char*)d_ws;
    int*   histB   = (int*)p;   p += ((size_t)NBIN * CB * 4 + 255) & ~(size_t)255;
    int*   binTot  = (int*)p;   p += ((size_t)NBIN * 4 + 255) & ~(size_t)255;
    int*   rp      = (int*)p;   p += ((size_t)(NN + 1) * 4 + 255) & ~(size_t)255;
    float* dinv    = (float*)p; p += ((size_t)NN * 4 + 255) & ~(size_t)255;
    int*   col     = (int*)p;   p += ((size_t)EE * 4 + 255) & ~(size_t)255;
    __half* bufA   = (__half*)p; p += ((size_t)NN * DD * 2 + 255) & ~(size_t)255;
    __half* bufB   = (__half*)p;                  // N*D halves (9.6 MB)
    int*   packed  = (int*)bufB;                  // EE ints, alias (dead early)

    // ---- CSR build: 4 dispatches, no global atomics, no serial scans ----
    k_hist<<<CB, 256, 0, stream>>>(ei, histB);
    k_scan_bins<<<NBIN, 256, 0, stream>>>(histB, binTot);
    k_scatter_bins<<<CB, 256, 0, stream>>>(ei, histB, binTot, packed);
    k_csr<<<NBIN, 256, 0, stream>>>(packed, binTot, rp, dinv, col, x, bufA);

    // ---- layer 1 (fused): bufB = fp16(dinv .* relu(agg(bufA) @ W1 + b1)) ----
    k_fused<0><<<(NN + 31) / 32, 384, 0, stream>>>(bufA, rp, col, dinv, W1, b1,
                                                   bufB, nullptr);

    // ---- layer 2 (fused): d_out = relu(agg(bufB) @ W2 + b2) ----
    k_fused<1><<<(NN + 31) / 32, 384, 0, stream>>>(bufB, rp, col, dinv, W2, b2,
                                                   nullptr, out);
}